// Round 1
// baseline (355.482 us; speedup 1.0000x reference)
//
#include <hip/hip_runtime.h>
#include <hip/hip_bf16.h>

// Eikonal3D: 64^3 grid, 128 Jacobi sweeps of Godunov upwind update, then
// trilinear interp at 4096 events + MSE loss.
// Inputs (setup_inputs order): vp[64^3] f32, station_loc[3] f32,
// event_loc[4096*3] f32, event_time[4096] f32, phase_time[4096] f32,
// n_iter[1] int (=128, fixed by setup_inputs; host must know launch count,
// so it is hardcoded -- a device-side value cannot drive host launch count
// under graph capture).
// Output: at[4096] f32 then loss[1] f32 (out_size = 4097).

#define NXg 64
#define NYg 64
#define NZg 64
#define NPTS (NXg * NYg * NZg)
#define BIGV 1000.0f
#define PADV 10000.0f   // BIG*10 pad value
#define NEV 4096

__global__ __launch_bounds__(256) void eik_init(const float* __restrict__ vp,
                                                const float* __restrict__ st,
                                                float* __restrict__ u,
                                                float* __restrict__ fh) {
    int idx = blockIdx.x * blockDim.x + threadIdx.x;
    if (idx >= NPTS) return;
    float v = vp[idx];
    fh[idx] = 1.0f / v;   // fh = (1/vp)*H, H=1

    int z = idx & 63;
    int y = (idx >> 6) & 63;
    int x = idx >> 12;

    float sx = st[0], sy = st[1], sz = st[2];
    int ix0 = min(max((int)floorf(sx), 0), NXg - 2);
    int iy0 = min(max((int)floorf(sy), 0), NYg - 2);
    int iz0 = min(max((int)floorf(sz), 0), NZg - 2);
    float xs = fminf(fmaxf(sx, 0.0f), (float)(NXg - 1));
    float ys = fminf(fmaxf(sy, 0.0f), (float)(NYg - 1));
    float zs = fminf(fmaxf(sz, 0.0f), (float)(NZg - 1));

    float val = BIGV;
    if (x >= ix0 && x <= ix0 + 1 && y >= iy0 && y <= iy0 + 1 &&
        z >= iz0 && z <= iz0 + 1) {
        float dx = xs - (float)x;
        float dy = ys - (float)y;
        float dz = zs - (float)z;
        float dist = sqrtf(dx * dx + dy * dy + dz * dz);
        val = dist / v;   // dist*H / vp[node]
    }
    u[idx] = val;
}

__global__ __launch_bounds__(256) void eik_godunov(const float* __restrict__ u,
                                                   float* __restrict__ un,
                                                   const float* __restrict__ fh) {
    int idx = blockIdx.x * blockDim.x + threadIdx.x;
    if (idx >= NPTS) return;
    int z = idx & 63;
    int y = (idx >> 6) & 63;
    int x = idx >> 12;

    float uc = u[idx];
    float xm = (x > 0)       ? u[idx - 4096] : PADV;
    float xp = (x < NXg - 1) ? u[idx + 4096] : PADV;
    float ym = (y > 0)       ? u[idx - 64]   : PADV;
    float yp = (y < NYg - 1) ? u[idx + 64]   : PADV;
    float zm = (z > 0)       ? u[idx - 1]    : PADV;
    float zp = (z < NZg - 1) ? u[idx + 1]    : PADV;

    float ax = fminf(xm, xp);
    float ay = fminf(ym, yp);
    float az = fminf(zm, zp);

    // exact 3-way sort (med3 idiom)
    float lo = fminf(ax, ay), hi = fmaxf(ax, ay);
    float a1 = fminf(lo, az);
    float a3 = fmaxf(hi, az);
    float a2 = fminf(fmaxf(lo, az), hi);

    float f = fh[idx];

    float x1 = a1 + f;
    float d12 = a1 - a2;
    float d2 = 2.0f * f * f - d12 * d12;
    float x2 = 0.5f * (a1 + a2 + sqrtf(fmaxf(d2, 0.0f)));
    float s = a1 + a2 + a3;
    float q = a1 * a1 + a2 * a2 + a3 * a3;
    float d3 = s * s - 3.0f * (q - f * f);
    float x3 = (s + sqrtf(fmaxf(d3, 0.0f))) * (1.0f / 3.0f);

    float unew = (x1 <= a2) ? x1 : ((x2 <= a3) ? x2 : x3);
    un[idx] = fminf(uc, unew);
}

__global__ __launch_bounds__(1024) void eik_finalize(const float* __restrict__ u,
                                                     const float* __restrict__ evloc,
                                                     const float* __restrict__ evtime,
                                                     const float* __restrict__ phtime,
                                                     float* __restrict__ out) {
    __shared__ float red[16];
    int t = threadIdx.x;
    float acc = 0.0f;
    for (int i = t; i < NEV; i += 1024) {
        float x = evloc[3 * i + 0];
        float y = evloc[3 * i + 1];
        float z = evloc[3 * i + 2];
        int ix0 = min(max((int)floorf(x), 0), NXg - 2);
        int iy0 = min(max((int)floorf(y), 0), NYg - 2);
        int iz0 = min(max((int)floorf(z), 0), NZg - 2);
        float xs = fminf(fmaxf(x, 0.0f), (float)(NXg - 1));
        float ys = fminf(fmaxf(y, 0.0f), (float)(NYg - 1));
        float zs = fminf(fmaxf(z, 0.0f), (float)(NZg - 1));
        float wx0 = xs - (float)ix0, wx1 = (float)(ix0 + 1) - xs;
        float wy0 = ys - (float)iy0, wy1 = (float)(iy0 + 1) - ys;
        float wz0 = zs - (float)iz0, wz1 = (float)(iz0 + 1) - zs;
        int base = ix0 * 4096 + iy0 * 64 + iz0;
        float c000 = u[base];
        float c100 = u[base + 4096];
        float c010 = u[base + 64];
        float c110 = u[base + 4096 + 64];
        float c001 = u[base + 1];
        float c101 = u[base + 4096 + 1];
        float c011 = u[base + 64 + 1];
        float c111 = u[base + 4096 + 64 + 1];
        float tt = c000 * wx1 * wy1 * wz1 + c100 * wx0 * wy1 * wz1
                 + c010 * wx1 * wy0 * wz1 + c110 * wx0 * wy0 * wz1
                 + c001 * wx1 * wy1 * wz0 + c101 * wx0 * wy1 * wz0
                 + c011 * wx1 * wy0 * wz0 + c111 * wx0 * wy0 * wz0;
        float at = evtime[i] + tt;
        out[i] = at;
        float d = at - phtime[i];
        acc += d * d;
    }
    // deterministic reduction: wave64 shuffle, then LDS across 16 waves
    #pragma unroll
    for (int off = 32; off > 0; off >>= 1) acc += __shfl_down(acc, off);
    if ((t & 63) == 0) red[t >> 6] = acc;
    __syncthreads();
    if (t < 16) {
        float v = red[t];
        #pragma unroll
        for (int off = 8; off > 0; off >>= 1) v += __shfl_down(v, off);
        if (t == 0) out[NEV] = v * (1.0f / (float)NEV);
    }
}

extern "C" void kernel_launch(void* const* d_in, const int* in_sizes, int n_in,
                              void* d_out, int out_size, void* d_ws, size_t ws_size,
                              hipStream_t stream) {
    const float* vp     = (const float*)d_in[0];
    const float* stloc  = (const float*)d_in[1];
    const float* evloc  = (const float*)d_in[2];
    const float* evtime = (const float*)d_in[3];
    const float* phtime = (const float*)d_in[4];
    // d_in[5] = n_iter (device scalar, fixed 128 by setup_inputs)
    float* out = (float*)d_out;

    float* w   = (float*)d_ws;
    float* u0  = w;              // 64^3
    float* u1  = w + NPTS;       // 64^3
    float* fh  = w + 2 * NPTS;   // 64^3

    const int NITER = 128;

    eik_init<<<NPTS / 256, 256, 0, stream>>>(vp, stloc, u0, fh);

    float* cur = u0;
    float* nxt = u1;
    for (int it = 0; it < NITER; ++it) {
        eik_godunov<<<NPTS / 256, 256, 0, stream>>>(cur, nxt, fh);
        float* tmp = cur; cur = nxt; nxt = tmp;
    }

    eik_finalize<<<1, 1024, 0, stream>>>(cur, evloc, evtime, phtime, out);
}